// Round 7
// baseline (7117.812 us; speedup 1.0000x reference)
//
#include <hip/hip_runtime.h>
#include <stdint.h>

using u16 = unsigned short;
typedef unsigned int u32;
typedef __attribute__((ext_vector_type(4))) float f32x4;
typedef __attribute__((ext_vector_type(8))) short short8;

typedef const __attribute__((address_space(1))) u32* gas_ptr;
typedef __attribute__((address_space(3))) u32* las_ptr;

// ---------- bf16 helpers (bit-level, RNE) ----------
__device__ __forceinline__ u16 f2bf_u(float f) {
    u32 u = __builtin_bit_cast(u32, f);
    u32 r = 0x7fffu + ((u >> 16) & 1u);
    return (u16)((u + r) >> 16);
}
__device__ __forceinline__ float bfu2f(u16 h) {
    u32 u = ((u32)h) << 16;
    return __builtin_bit_cast(float, u);
}
__device__ __forceinline__ void split2(float v, u16& hi, u16& lo) {
    hi = f2bf_u(v);
    lo = f2bf_u(v - bfu2f(hi));   // exact residual, ~16 mantissa bits total
}

__device__ __forceinline__ void gload16(const void* g, void* l) {
    __builtin_amdgcn_global_load_lds((gas_ptr)g, (las_ptr)l, 16, 0, 0);
}

// ---------- GEMM-BT 256x256 tile, BK=32, 8 waves ----------
// 3-phase product-split interleave per K-tile (m201-style, adapted):
//   P1: issue STAGE(t+2)+BLOQ(t+1) VMEM, then ALL 20 ds_reads, then 32 MFMA
//       (Ahi*Bhi) -- al reads complete under these MFMAs (compiler emits
//       counted lgkm waits per use).
//   P2: 32 MFMA (Alo*Bhi), zero reads.
//   P3: counted s_waitcnt vmcnt -> 32 MFMA (Ahi*Blo-regs) -> s_barrier.
// vmcnt ledger (SPLIT, groups S=6 gload_lds + Q=4 reg loads per tile, issued
// [S(t+2),Q(t+1)] at tile t P1): at t P3 outstanding <= S(t+1),Q(t),S(t+2),
// Q(t+1)=20; need S(t+1),Q(t) done -> wait vmcnt(10). Tails: t=NT-2 ->
// vmcnt(4) (only Q(NT-1) newer), t=NT-1 -> vmcnt(0). Non-split S=4: 4/0.
// Prologue: S(0),Q(0),S(1) -> need S(0) -> vmcnt(10|4); barrier.
// LDS chunk swizzle (verified 0 conflicts): slot (row,c) holds global chunk
// c ^ ((row>>1)&3); staged via pre-swizzled GLOBAL source (LDS dest linear,
// global_load_lds rule), read with matching XOR.
// EPI 0: v=acc+aux[col]; relu; bf16 split write (out0=hi,out1=lo), [M][N]
// EPI 1: v=acc+aux[col]; bf16 split scatter to [b][col][c] (b=row>>9,c=row&511)
// EPI 2: fp32 row-major write (scores; per-row scale applied in softmax)
// EPI 3: fp32 write with batch stride (preLN)

#define STAGE(CBUF, KT)                                                      \
  {                                                                          \
    const int kk_ = (KT) << 5;                                               \
    _Pragma("unroll")                                                        \
    for (int it_ = 0; it_ < 2; ++it_) {                                      \
      const int rb_ = it_ * 128 + w * 16;                                    \
      const int lo_ = (CBUF) * 8192 + rb_ * 32;                              \
      const size_t ga_ = (size_t)(brow + rb_ + srow) * lda + (kk_ + sca);    \
      const size_t gb_ = (size_t)(bcol + rb_ + srow) * lda + (kk_ + sca);    \
      gload16(A0 + ga_, &As0[lo_]);                                          \
      gload16(B0 + gb_, &Bs0[lo_]);                                          \
      if constexpr (SPLIT) gload16(A1 + ga_, &As1[lo_]);                     \
    }                                                                        \
  }

#define BLOQ(Q, KT)                                                          \
  {                                                                          \
    const u16* bb_ = B1 + (size_t)(bcol + wc * 64 + lr) * lda                \
                     + (((KT) << 5) + ((l >> 4) * 8));                       \
    _Pragma("unroll")                                                        \
    for (int n_ = 0; n_ < 4; ++n_)                                           \
      Q[n_] = *(const short8*)(bb_ + (size_t)(n_ * 16) * lda);               \
  }

#define TILE(KT, CB, QCUR, QNXT)                                             \
  {                                                                          \
    /* P1a: issue next-tile VMEM first (earliest flight) */                  \
    if ((KT) + 2 < NT) {                                                     \
      int cs_ = (CB) + 2; if (cs_ >= 3) cs_ -= 3;                            \
      STAGE(cs_, (KT) + 2);                                                  \
    }                                                                        \
    if constexpr (SPLIT) { if ((KT) + 1 < NT) BLOQ(QNXT, (KT) + 1); }        \
    __builtin_amdgcn_sched_barrier(0);                                       \
    /* P1b: all ds_reads for this tile */                                    \
    short8 bh_[4], ah0_[4], ah1_[4], al0_[4], al1_[4];                       \
    _Pragma("unroll")                                                        \
    for (int n_ = 0; n_ < 4; ++n_)                                           \
      bh_[n_] = *(const short8*)&Bs0[(CB) * 8192 +                           \
                                     (wc * 64 + n_ * 16 + lr) * 32 + cr];    \
    _Pragma("unroll")                                                        \
    for (int m_ = 0; m_ < 4; ++m_) {                                         \
      const int r0_ = (CB) * 8192 + (wr * 128 + m_ * 16 + lr) * 32 + cr;     \
      ah0_[m_] = *(const short8*)&As0[r0_];                                  \
      ah1_[m_] = *(const short8*)&As0[r0_ + 64 * 32];                        \
      if constexpr (SPLIT) {                                                 \
        al0_[m_] = *(const short8*)&As1[r0_];                                \
        al1_[m_] = *(const short8*)&As1[r0_ + 64 * 32];                      \
      }                                                                      \
    }                                                                        \
    __builtin_amdgcn_sched_barrier(0);                                       \
    /* P1c: product 1 (Ahi*Bhi) */                                           \
    __builtin_amdgcn_s_setprio(1);                                           \
    _Pragma("unroll")                                                        \
    for (int m_ = 0; m_ < 4; ++m_)                                           \
      _Pragma("unroll")                                                      \
      for (int n_ = 0; n_ < 4; ++n_) {                                       \
        acc[m_][n_] = __builtin_amdgcn_mfma_f32_16x16x32_bf16(               \
            ah0_[m_], bh_[n_], acc[m_][n_], 0, 0, 0);                        \
        acc[4 + m_][n_] = __builtin_amdgcn_mfma_f32_16x16x32_bf16(           \
            ah1_[m_], bh_[n_], acc[4 + m_][n_], 0, 0, 0);                    \
      }                                                                      \
    __builtin_amdgcn_s_setprio(0);                                           \
    __builtin_amdgcn_sched_barrier(0);                                       \
    if constexpr (SPLIT) {                                                   \
      /* P2: product 2 (Alo*Bhi) */                                          \
      __builtin_amdgcn_s_setprio(1);                                         \
      _Pragma("unroll")                                                      \
      for (int m_ = 0; m_ < 4; ++m_)                                         \
        _Pragma("unroll")                                                    \
        for (int n_ = 0; n_ < 4; ++n_) {                                     \
          acc[m_][n_] = __builtin_amdgcn_mfma_f32_16x16x32_bf16(             \
              al0_[m_], bh_[n_], acc[m_][n_], 0, 0, 0);                      \
          acc[4 + m_][n_] = __builtin_amdgcn_mfma_f32_16x16x32_bf16(         \
              al1_[m_], bh_[n_], acc[4 + m_][n_], 0, 0, 0);                  \
        }                                                                    \
      __builtin_amdgcn_s_setprio(0);                                         \
      __builtin_amdgcn_sched_barrier(0);                                     \
    }                                                                        \
    /* P3: counted vmcnt (never 0 mid-loop), then product 3 */               \
    if ((KT) + 2 < NT) {                                                     \
      if constexpr (SPLIT)                                                   \
        asm volatile("s_waitcnt vmcnt(10)" ::: "memory");                    \
      else                                                                   \
        asm volatile("s_waitcnt vmcnt(4)" ::: "memory");                     \
    } else if ((KT) + 1 < NT) {                                              \
      if constexpr (SPLIT)                                                   \
        asm volatile("s_waitcnt vmcnt(4)" ::: "memory");                     \
      else                                                                   \
        asm volatile("s_waitcnt vmcnt(0)" ::: "memory");                     \
    } else {                                                                 \
      asm volatile("s_waitcnt vmcnt(0)" ::: "memory");                       \
    }                                                                        \
    __builtin_amdgcn_sched_barrier(0);                                       \
    if constexpr (SPLIT) {                                                   \
      __builtin_amdgcn_s_setprio(1);                                         \
      _Pragma("unroll")                                                      \
      for (int m_ = 0; m_ < 4; ++m_)                                         \
        _Pragma("unroll")                                                    \
        for (int n_ = 0; n_ < 4; ++n_) {                                     \
          acc[m_][n_] = __builtin_amdgcn_mfma_f32_16x16x32_bf16(             \
              ah0_[m_], QCUR[n_], acc[m_][n_], 0, 0, 0);                     \
          acc[4 + m_][n_] = __builtin_amdgcn_mfma_f32_16x16x32_bf16(         \
              ah1_[m_], QCUR[n_], acc[4 + m_][n_], 0, 0, 0);                 \
        }                                                                    \
      __builtin_amdgcn_s_setprio(0);                                         \
    }                                                                        \
    __builtin_amdgcn_s_barrier();                                            \
    __builtin_amdgcn_sched_barrier(0);                                       \
  }

template<int EPI, bool SPLIT>
__global__ __launch_bounds__(512, 2)
void gemm256(const u16* __restrict__ Ah, const u16* __restrict__ Al,
             const u16* __restrict__ Bh, const u16* __restrict__ Bl,
             int K, int lda, int N,
             const float* __restrict__ aux,
             void* __restrict__ out0, void* __restrict__ out1,
             size_t strideA, size_t strideB, size_t strideO)
{
    extern __shared__ __align__(16) u16 lds[];
    u16* const As0 = lds;                                   // [3][8192]
    u16* const Bs0 = lds + 3 * 8192;                        // [3][8192]
    u16* const As1 = SPLIT ? (lds + 6 * 8192) : lds;        // [3][8192]

    const int t = threadIdx.x;
    const int w = t >> 6;
    const int l = t & 63;

    // Block swizzle. 16x16 grids: 4x8 region per XCD; other grids: generic
    // XCD-chunked bijective swizzle (nwg % 8 == 0).
    int brow, bcol;
    const int gx = gridDim.x, gy = gridDim.y;
    const int orig = blockIdx.y * gx + blockIdx.x;
    if (gx == 16 && gy == 16) {
        const int x = orig & 7, j = orig >> 3;
        brow = ((x & 3) * 4 + (j & 3)) * 256;
        bcol = ((x >> 2) * 8 + (j >> 2)) * 256;
    } else {
        const int nwg = gx * gy;
        const int swz = (orig & 7) * (nwg >> 3) + (orig >> 3);
        brow = (swz / gx) * 256;
        bcol = (swz % gx) * 256;
    }
    const int z = blockIdx.z;

    const u16* A0 = Ah + (size_t)z * strideA;
    const u16* A1 = SPLIT ? (Al + (size_t)z * strideA) : nullptr;
    const u16* B0 = Bh + (size_t)z * strideB;
    const u16* B1 = SPLIT ? (Bl + (size_t)z * strideB) : nullptr;

    // staging: lane l covers row l>>2 (of 16), LDS chunk l&3;
    // global chunk = (l&3) ^ ((row>>1)&3) = (l&3) ^ ((l>>3)&3)
    const int srow = l >> 2;
    const int sca = ((l & 3) ^ ((l >> 3) & 3)) * 8;

    // wave grid 2(M) x 4(N)
    const int wr = w >> 2;
    const int wc = w & 3;
    const int lr = l & 15;
    // frag read swizzle: slot chunk = (l>>4) ^ ((row>>1)&3), row%16 = lr
    const int cr = ((l >> 4) ^ ((l >> 1) & 3)) * 8;

    f32x4 acc[8][4];
    const f32x4 zero = {0.f, 0.f, 0.f, 0.f};
#pragma unroll
    for (int i = 0; i < 8; ++i)
#pragma unroll
        for (int j = 0; j < 4; ++j) acc[i][j] = zero;

    const int NT = K >> 5;
    short8 qA[4], qB[4];

    // prologue: S(0), Q(0), S(1); wait S(0); barrier
    STAGE(0, 0);
    if constexpr (SPLIT) BLOQ(qA, 0);
    STAGE(1, 1);
    if constexpr (SPLIT)
        asm volatile("s_waitcnt vmcnt(10)" ::: "memory");
    else
        asm volatile("s_waitcnt vmcnt(4)" ::: "memory");
    __builtin_amdgcn_s_barrier();
    __builtin_amdgcn_sched_barrier(0);

    int cb = 0;
    for (int kt = 0; kt < NT; kt += 2) {
        TILE(kt, cb, qA, qB);
        cb = (cb == 2) ? 0 : cb + 1;
        TILE(kt + 1, cb, qB, qA);
        cb = (cb == 2) ? 0 : cb + 1;
    }

#pragma unroll
    for (int mh = 0; mh < 2; ++mh)
#pragma unroll
        for (int m = 0; m < 4; ++m)
#pragma unroll
            for (int n = 0; n < 4; ++n)
#pragma unroll
                for (int j = 0; j < 4; ++j) {
                    const int row = brow + wr * 128 + mh * 64 + m * 16 + (l >> 4) * 4 + j;
                    const int col = bcol + wc * 64 + n * 16 + (l & 15);
                    float v = acc[mh * 4 + m][n][j];
                    if (EPI == 0) {
                        v += aux[col];
                        v = fmaxf(v, 0.f);
                        u16 hi, lo; split2(v, hi, lo);
                        ((u16*)out0)[(size_t)row * N + col] = hi;
                        ((u16*)out1)[(size_t)row * N + col] = lo;
                    } else if (EPI == 1) {
                        v += aux[col];
                        const int bb = row >> 9, cc = row & 511;
                        const size_t idx = ((size_t)bb * N + col) * 512 + cc;
                        u16 hi, lo; split2(v, hi, lo);
                        ((u16*)out0)[idx] = hi;
                        ((u16*)out1)[idx] = lo;
                    } else if (EPI == 2) {
                        ((float*)out0)[(size_t)row * N + col] = v;
                    } else {
                        ((float*)out0)[(size_t)z * strideO + (size_t)row * N + col] = v;
                    }
                }
}

// ---------- elementwise split fp32 -> (hi,lo) bf16 ----------
__global__ void split_k(const float* __restrict__ in, u16* __restrict__ hi,
                        u16* __restrict__ lo, size_t n4)
{
    size_t i = blockIdx.x * (size_t)blockDim.x + threadIdx.x;
    const size_t stride = (size_t)gridDim.x * blockDim.x;
    for (; i < n4; i += stride) {
        const float4 v = ((const float4*)in)[i];
        ushort4 h, l;
        split2(v.x, h.x, l.x);
        split2(v.y, h.y, l.y);
        split2(v.z, h.z, l.z);
        split2(v.w, h.w, l.w);
        ((ushort4*)hi)[i] = h;
        ((ushort4*)lo)[i] = l;
    }
}

// ---------- plain fp32 -> bf16 convert ----------
__global__ void conv_bf16_k(const float* __restrict__ in, u16* __restrict__ out, size_t n4)
{
    size_t i = blockIdx.x * (size_t)blockDim.x + threadIdx.x;
    const size_t stride = (size_t)gridDim.x * blockDim.x;
    for (; i < n4; i += stride) {
        const float4 v = ((const float4*)in)[i];
        ushort4 o;
        o.x = f2bf_u(v.x); o.y = f2bf_u(v.y); o.z = f2bf_u(v.z); o.w = f2bf_u(v.w);
        ((ushort4*)out)[i] = o;
    }
}

// ---------- x (B,512,4096) -> xt (B,4096,512) with bf16 hi/lo split ----------
__global__ void transpose_split_x(const float* __restrict__ x,
                                  u16* __restrict__ xt_hi, u16* __restrict__ xt_lo)
{
    __shared__ float tile[32][33];
    const int b = blockIdx.z;
    const int n0 = blockIdx.x * 32;
    const int c0 = blockIdx.y * 32;
    const int tx = threadIdx.x, ty = threadIdx.y;   // block (32,8)
#pragma unroll
    for (int k = 0; k < 4; ++k)
        tile[ty + 8 * k][tx] = x[((size_t)b * 512 + c0 + ty + 8 * k) * 4096 + n0 + tx];
    __syncthreads();
#pragma unroll
    for (int k = 0; k < 4; ++k) {
        const float v = tile[tx][ty + 8 * k];       // [c_local][n_local]
        u16 hi, lo; split2(v, hi, lo);
        const size_t idx = ((size_t)b * 4096 + n0 + ty + 8 * k) * 512 + c0 + tx;
        xt_hi[idx] = hi;
        xt_lo[idx] = lo;
    }
}

// ---------- scale vector: s[n] = exp(min(ls[n], log(100))) ----------
__global__ void scale_prep(const float* __restrict__ ls, float* __restrict__ s)
{
    const int i = blockIdx.x * blockDim.x + threadIdx.x;
    if (i < 4096) s[i] = expf(fminf(ls[i], 4.605170185988092f));
}

// ---------- row softmax of tempT (4096 cols), row-scale s[m], write bf16 P ----------
__global__ __launch_bounds__(256)
void softmax_rows(const float* __restrict__ T, const float* __restrict__ s, u16* __restrict__ P)
{
    const int m = blockIdx.x;
    const int t = threadIdx.x;
    const float sc = s[m];
    const float* row = T + (size_t)m * 4096;
    float v[16];
    float mx = -3.402823e38f;
#pragma unroll
    for (int i = 0; i < 16; ++i) {
        v[i] = row[t + 256 * i] * sc;
        mx = fmaxf(mx, v[i]);
    }
#pragma unroll
    for (int o = 32; o; o >>= 1) mx = fmaxf(mx, __shfl_xor(mx, o, 64));
    __shared__ float sm[4], ss[4];
    if ((t & 63) == 0) sm[t >> 6] = mx;
    __syncthreads();
    mx = fmaxf(fmaxf(sm[0], sm[1]), fmaxf(sm[2], sm[3]));
    float sum = 0.f;
#pragma unroll
    for (int i = 0; i < 16; ++i) {
        v[i] = expf(v[i] - mx);
        sum += v[i];
    }
#pragma unroll
    for (int o = 32; o; o >>= 1) sum += __shfl_xor(sum, o, 64);
    if ((t & 63) == 0) ss[t >> 6] = sum;
    __syncthreads();
    sum = (ss[0] + ss[1]) + (ss[2] + ss[3]);
    const float inv = 1.f / sum;
#pragma unroll
    for (int i = 0; i < 16; ++i)
        P[(size_t)m * 4096 + t + 256 * i] = f2bf_u(v[i] * inv);
}

// ---------- LayerNorm rows of 4096 ----------
__global__ __launch_bounds__(256)
void ln_rows(const float* __restrict__ X, const float* __restrict__ gw,
             const float* __restrict__ gb, float* __restrict__ out)
{
    const int r = blockIdx.x;
    const int t = threadIdx.x;
    const float* row = X + (size_t)r * 4096;
    float v[16];
    float s1 = 0.f, s2 = 0.f;
#pragma unroll
    for (int i = 0; i < 16; ++i) {
        v[i] = row[t + 256 * i];
        s1 += v[i];
        s2 += v[i] * v[i];
    }
#pragma unroll
    for (int o = 32; o; o >>= 1) {
        s1 += __shfl_xor(s1, o, 64);
        s2 += __shfl_xor(s2, o, 64);
    }
    __shared__ float m1[4], m2[4];
    if ((t & 63) == 0) { m1[t >> 6] = s1; m2[t >> 6] = s2; }
    __syncthreads();
    s1 = (m1[0] + m1[1]) + (m1[2] + m1[3]);
    s2 = (m2[0] + m2[1]) + (m2[2] + m2[3]);
    const float mu = s1 * (1.f / 4096.f);
    const float var = s2 * (1.f / 4096.f) - mu * mu;
    const float rs = rsqrtf(var + 1e-5f);
#pragma unroll
    for (int i = 0; i < 16; ++i) {
        const int n = t + 256 * i;
        out[(size_t)r * 4096 + n] = (v[i] - mu) * rs * gw[n] + gb[n];
    }
}

extern "C" void kernel_launch(void* const* d_in, const int* in_sizes, int n_in,
                              void* d_out, int out_size, void* d_ws, size_t ws_size,
                              hipStream_t stream)
{
    const float* x  = (const float*)d_in[0];
    const float* fe = (const float*)d_in[1];
    const float* w1 = (const float*)d_in[2];
    const float* b1 = (const float*)d_in[3];
    const float* w2 = (const float*)d_in[4];
    const float* b2 = (const float*)d_in[5];
    const float* ls = (const float*)d_in[6];
    const float* nw = (const float*)d_in[7];
    const float* nb = (const float*)d_in[8];
    float* out = (float*)d_out;
    char* ws = (char*)d_ws;

    if (ws_size < 637550592ull) return;

    // Dynamic-LDS caps (host-side attribute, graph-capture safe).
    hipFuncSetAttribute((const void*)gemm256<0, true>,
                        hipFuncAttributeMaxDynamicSharedMemorySize, 147456);
    hipFuncSetAttribute((const void*)gemm256<1, true>,
                        hipFuncAttributeMaxDynamicSharedMemorySize, 147456);
    hipFuncSetAttribute((const void*)gemm256<2, true>,
                        hipFuncAttributeMaxDynamicSharedMemorySize, 147456);
    hipFuncSetAttribute((const void*)gemm256<3, false>,
                        hipFuncAttributeMaxDynamicSharedMemorySize, 98304);

    // Workspace plan (stream-order lifetime reuse):
    u16*  fhi  = (u16*) (ws + 0ull);
    u16*  flo  = (u16*) (ws + 134217728ull);
    u16*  w1hi = (u16*) (ws + 268435456ull);
    u16*  w1lo = (u16*) (ws + 402653184ull);
    u16*  hhi  = (u16*) (ws + 536870912ull);
    u16*  hlo  = (u16*) (ws + 570425344ull);
    u16*  w2hi = (u16*) (ws + 0ull);           // fe region dead after GEMM1
    u16*  w2lo = (u16*) (ws + 33554432ull);
    u16*  fthi = (u16*) (ws + 67108864ull);
    u16*  ftlo = (u16*) (ws + 100663296ull);
    u16*  xthi = (u16*) (ws + 134217728ull);
    u16*  xtlo = (u16*) (ws + 167772160ull);
    u16*  xbf  = (u16*) (ws + 201326592ull);
    float* tt  = (float*)(ws + 234881024ull);   // one-batch scores, fp32
    u16*  pall = (u16*) (ws + 301989888ull);    // P bf16, all batches
    float* pre = (float*)(ws + 570425344ull);   // pre-LN fp32 (h dead)
    float* sv  = (float*)(ws + 637534208ull);

    // 1. split feature and fc1_w
    split_k<<<2048, 256, 0, stream>>>(fe, fhi, flo, (size_t)16777216);
    split_k<<<2048, 256, 0, stream>>>(w1, w1hi, w1lo, (size_t)16777216);

    // 2. GEMM1: h = relu(feature @ fc1_w^T + b1), split-3, 3-phase interleave
    gemm256<0, true><<<dim3(16, 16, 1), 512, 147456, stream>>>(
        fhi, flo, w1hi, w1lo, 16384, 16384, 4096, b1, hhi, hlo, 0, 0, 0);

    // 3. split fc2_w (fe region dead after GEMM1 in stream order)
    split_k<<<2048, 256, 0, stream>>>(w2, w2hi, w2lo, (size_t)4194304);

    // 4. GEMM2: feat = h @ fc2_w^T + b2, split scatter to ft[b][n][c]
    gemm256<1, true><<<dim3(16, 16, 1), 512, 147456, stream>>>(
        hhi, hlo, w2hi, w2lo, 4096, 4096, 4096, b2, fthi, ftlo, 0, 0, 0);

    // 5. x transforms + scale vector
    transpose_split_x<<<dim3(128, 16, 8), dim3(32, 8), 0, stream>>>(x, xthi, xtlo);
    conv_bf16_k<<<2048, 256, 0, stream>>>(x, xbf, (size_t)4194304);
    scale_prep<<<16, 256, 0, stream>>>(ls, sv);

    // 6. per batch: scores GEMM (split-3, K=512) + row softmax -> P
    for (int b = 0; b < 8; ++b) {
        const size_t o = (size_t)b * 4096 * 512;
        gemm256<2, true><<<dim3(16, 16, 1), 512, 147456, stream>>>(
            xthi + o, xtlo + o, fthi + o, ftlo + o, 512, 512, 4096,
            nullptr, tt, nullptr, 0, 0, 0);
        softmax_rows<<<4096, 256, 0, stream>>>(tt, sv, pall + (size_t)b * 16777216);
    }

    // 7. GEMM4: pre[b][c][m] = sum_n x[b][c][n] * P[b][m][n]   (plain bf16)
    gemm256<3, false><<<dim3(16, 2, 8), 512, 98304, stream>>>(
        xbf, nullptr, pall, nullptr, 4096, 4096, 4096, nullptr, pre, nullptr,
        (size_t)512 * 4096, (size_t)4096 * 4096, (size_t)512 * 4096);

    // 8. LayerNorm
    ln_rows<<<4096, 256, 0, stream>>>(pre, nw, nb, out);
}

// Round 8
// 2953.410 us; speedup vs baseline: 2.4100x; 2.4100x over previous
//
#include <hip/hip_runtime.h>
#include <stdint.h>

using u16 = unsigned short;
typedef unsigned int u32;
typedef __attribute__((ext_vector_type(16))) float f32x16;
typedef __attribute__((ext_vector_type(8))) short short8;

typedef const __attribute__((address_space(1))) u32* gas_ptr;
typedef __attribute__((address_space(3))) u32* las_ptr;

// ---------- bf16 helpers (bit-level, RNE) ----------
__device__ __forceinline__ u16 f2bf_u(float f) {
    u32 u = __builtin_bit_cast(u32, f);
    u32 r = 0x7fffu + ((u >> 16) & 1u);
    return (u16)((u + r) >> 16);
}
__device__ __forceinline__ float bfu2f(u16 h) {
    u32 u = ((u32)h) << 16;
    return __builtin_bit_cast(float, u);
}
__device__ __forceinline__ void split2(float v, u16& hi, u16& lo) {
    hi = f2bf_u(v);
    lo = f2bf_u(v - bfu2f(hi));   // exact residual, ~16 mantissa bits total
}

__device__ __forceinline__ void gload16(const void* g, void* l) {
    __builtin_amdgcn_global_load_lds((gas_ptr)g, (las_ptr)l, 16, 0, 0);
}

// ---------- GEMM-BT 256x256 tile, BK=32, 8 waves, mfma 32x32x16 ----------
// Round-5 proven pipeline (counted vmcnt, depth-2, 3 LDS buffers), fragments
// switched to v_mfma_f32_32x32x16_bf16 (1015 vs 844 FLOP/cyc/SIMD, 48 vs 96
// MFMA per wave-tile).
//   LDS: 3 bufs x {Ahi, Bhi, (Alo)}; Blo in per-wave register frags (BLOQ).
//   Per K-tile: s_waitcnt vmcnt(10|4) -> s_barrier -> STAGE(kt+2) -> reads
//   + 48|16 MFMA -> BLOQ(kt+2). vmcnt never drains to 0 mid-loop.
// Ledger (SPLIT): groups per tile = [S:6 gload_lds][Q:4 reg loads]; at tile t
// top, outstanding = S(t),Q(t),S(t+1),Q(t+1)=20 -> wait 10 leaves S/Q(t+1).
// Tail t=NT-1 -> vmcnt(0). Non-split: S=4 -> wait 4 / 0.
// LDS chunk swizzle (verified 0 conflicts): slot (row,c) holds global chunk
// c ^ ((row>>1)&3); staged via pre-swizzled GLOBAL source (LDS dest linear),
// read with matching XOR: for 32x32 frags, lane l -> row l&31, global chunk
// g = s*2+(l>>5), slot chunk g ^ ((l>>1)&3).
// C/D layout (m74/m101): col = lane&31, row = (reg&3)+8*(reg>>2)+4*(lane>>5).
// EPI 0: v=acc+aux[col]; relu; bf16 split write (out0=hi,out1=lo), [M][N]
// EPI 1: v=acc+aux[col]; bf16 split scatter to [b][col][c] (b=row>>9,c=row&511)
// EPI 2: fp32 row-major write (scores; per-row scale applied in softmax)
// EPI 3: fp32 write with batch stride (preLN)

#define STAGE(CBUF, KT)                                                      \
  {                                                                          \
    const int kk_ = (KT) << 5;                                               \
    _Pragma("unroll")                                                        \
    for (int it_ = 0; it_ < 2; ++it_) {                                      \
      const int rb_ = it_ * 128 + w * 16;                                    \
      const int lo_ = (CBUF) * 8192 + rb_ * 32;                              \
      const size_t ga_ = (size_t)(brow + rb_ + srow) * lda + (kk_ + sca);    \
      const size_t gb_ = (size_t)(bcol + rb_ + srow) * lda + (kk_ + sca);    \
      gload16(A0 + ga_, &As0[lo_]);                                          \
      gload16(B0 + gb_, &Bs0[lo_]);                                          \
      if constexpr (SPLIT) gload16(A1 + ga_, &As1[lo_]);                     \
    }                                                                        \
  }

#define BLOQ(Q, KT)                                                          \
  {                                                                          \
    const u16* bb_ = B1 + (size_t)(bcol + wc * 64 + l31) * lda               \
                     + (((KT) << 5) + hi5 * 8);                              \
    Q[0] = *(const short8*)(bb_);                          /* cg0 s0 */      \
    Q[1] = *(const short8*)(bb_ + 16);                     /* cg0 s1 */      \
    Q[2] = *(const short8*)(bb_ + (size_t)32 * lda);       /* cg1 s0 */      \
    Q[3] = *(const short8*)(bb_ + (size_t)32 * lda + 16);  /* cg1 s1 */      \
  }

#define PHASE(KT, CB, Q)                                                     \
  {                                                                          \
    if ((KT) == NT - 1) {                                                    \
      asm volatile("s_waitcnt vmcnt(0)" ::: "memory");                       \
    } else {                                                                 \
      if constexpr (SPLIT) asm volatile("s_waitcnt vmcnt(10)" ::: "memory"); \
      else asm volatile("s_waitcnt vmcnt(4)" ::: "memory");                  \
    }                                                                        \
    __builtin_amdgcn_s_barrier();                                            \
    __builtin_amdgcn_sched_barrier(0);                                       \
    {                                                                        \
      int cs_ = (CB) + 2; if (cs_ >= 3) cs_ -= 3;                            \
      if ((KT) + 2 < NT) STAGE(cs_, (KT) + 2);                               \
    }                                                                        \
    short8 bh_[2][2];                                                        \
    _Pragma("unroll")                                                        \
    for (int cg_ = 0; cg_ < 2; ++cg_)                                        \
      _Pragma("unroll")                                                      \
      for (int s_ = 0; s_ < 2; ++s_)                                         \
        bh_[cg_][s_] = *(const short8*)&Bs0[(CB) * 8192 +                    \
            (wc * 64 + cg_ * 32 + l31) * 32 + crs[s_]];                      \
    _Pragma("unroll")                                                        \
    for (int rg_ = 0; rg_ < 4; ++rg_) {                                      \
      short8 ah_[2], al_[2];                                                 \
      const int ro_ = (CB) * 8192 + (wr * 128 + rg_ * 32 + l31) * 32;        \
      _Pragma("unroll")                                                      \
      for (int s_ = 0; s_ < 2; ++s_) {                                       \
        ah_[s_] = *(const short8*)&As0[ro_ + crs[s_]];                       \
        if constexpr (SPLIT) al_[s_] = *(const short8*)&As1[ro_ + crs[s_]];  \
      }                                                                      \
      __builtin_amdgcn_s_setprio(1);                                         \
      _Pragma("unroll")                                                      \
      for (int s_ = 0; s_ < 2; ++s_) {                                       \
        _Pragma("unroll")                                                    \
        for (int cg_ = 0; cg_ < 2; ++cg_)                                    \
          acc[rg_][cg_] = __builtin_amdgcn_mfma_f32_32x32x16_bf16(           \
              ah_[s_], bh_[cg_][s_], acc[rg_][cg_], 0, 0, 0);                \
        if constexpr (SPLIT) {                                               \
          _Pragma("unroll")                                                  \
          for (int cg_ = 0; cg_ < 2; ++cg_)                                  \
            acc[rg_][cg_] = __builtin_amdgcn_mfma_f32_32x32x16_bf16(         \
                al_[s_], bh_[cg_][s_], acc[rg_][cg_], 0, 0, 0);              \
          _Pragma("unroll")                                                  \
          for (int cg_ = 0; cg_ < 2; ++cg_)                                  \
            acc[rg_][cg_] = __builtin_amdgcn_mfma_f32_32x32x16_bf16(         \
                ah_[s_], Q[cg_ * 2 + s_], acc[rg_][cg_], 0, 0, 0);           \
        }                                                                    \
      }                                                                      \
      __builtin_amdgcn_s_setprio(0);                                         \
    }                                                                        \
    __builtin_amdgcn_sched_barrier(0);                                       \
    if ((KT) + 2 < NT) { if constexpr (SPLIT) BLOQ(Q, (KT) + 2); }           \
    __builtin_amdgcn_sched_barrier(0);                                       \
  }

template<int EPI, bool SPLIT>
__global__ __launch_bounds__(512, 2)
void gemm256(const u16* __restrict__ Ah, const u16* __restrict__ Al,
             const u16* __restrict__ Bh, const u16* __restrict__ Bl,
             int K, int lda, int N,
             const float* __restrict__ aux,
             void* __restrict__ out0, void* __restrict__ out1,
             size_t strideA, size_t strideB, size_t strideO)
{
    extern __shared__ __align__(16) u16 lds[];
    u16* const As0 = lds;                                   // [3][8192]
    u16* const Bs0 = lds + 3 * 8192;                        // [3][8192]
    u16* const As1 = SPLIT ? (lds + 6 * 8192) : lds;        // [3][8192]

    const int t = threadIdx.x;
    const int w = t >> 6;
    const int l = t & 63;

    // Block swizzle. 16x16 grids: 4x8 region per XCD; other grids: generic
    // XCD-chunked bijective swizzle (nwg % 8 == 0).
    int brow, bcol;
    const int gx = gridDim.x, gy = gridDim.y;
    const int orig = blockIdx.y * gx + blockIdx.x;
    if (gx == 16 && gy == 16) {
        const int x = orig & 7, j = orig >> 3;
        brow = ((x & 3) * 4 + (j & 3)) * 256;
        bcol = ((x >> 2) * 8 + (j >> 2)) * 256;
    } else {
        const int nwg = gx * gy;
        const int swz = (orig & 7) * (nwg >> 3) + (orig >> 3);
        brow = (swz / gx) * 256;
        bcol = (swz % gx) * 256;
    }
    const int z = blockIdx.z;

    const u16* A0 = Ah + (size_t)z * strideA;
    const u16* A1 = SPLIT ? (Al + (size_t)z * strideA) : nullptr;
    const u16* B0 = Bh + (size_t)z * strideB;
    const u16* B1 = SPLIT ? (Bl + (size_t)z * strideB) : nullptr;

    // staging: lane l covers row l>>2 (of 16), LDS chunk l&3;
    // global chunk for that slot = (l&3) ^ ((row>>1)&3) = (l&3) ^ ((l>>3)&3)
    const int srow = l >> 2;
    const int sca = ((l & 3) ^ ((l >> 3) & 3)) * 8;

    // wave grid 2(M) x 4(N); 32x32 fragment indices
    const int wr = w >> 2;
    const int wc = w & 3;
    const int l31 = l & 31;
    const int hi5 = l >> 5;
    const int csw = (l >> 1) & 3;          // ((row)>>1)&3 for row = base+l31
    int crs[2];
    crs[0] = ((hi5) ^ csw) * 8;            // k-slice s=0: global chunk hi5
    crs[1] = ((2 + hi5) ^ csw) * 8;        // k-slice s=1: global chunk 2+hi5

    f32x16 acc[4][2];
#pragma unroll
    for (int i = 0; i < 4; ++i)
#pragma unroll
        for (int j = 0; j < 2; ++j)
#pragma unroll
            for (int r = 0; r < 16; ++r) acc[i][j][r] = 0.f;

    const int NT = K >> 5;
    short8 qA[4], qB[4];

    // prologue: S(0), Q(0), S(1), Q(1); wait S(0); barrier
    STAGE(0, 0);
    if constexpr (SPLIT) BLOQ(qA, 0);
    STAGE(1, 1);
    if constexpr (SPLIT) BLOQ(qB, 1);
    if constexpr (SPLIT)
        asm volatile("s_waitcnt vmcnt(10)" ::: "memory");
    else
        asm volatile("s_waitcnt vmcnt(4)" ::: "memory");
    __builtin_amdgcn_s_barrier();
    __builtin_amdgcn_sched_barrier(0);

    int cb = 0;
    for (int kt = 0; kt < NT; kt += 2) {
        PHASE(kt, cb, qA);
        cb = (cb == 2) ? 0 : cb + 1;
        PHASE(kt + 1, cb, qB);
        cb = (cb == 2) ? 0 : cb + 1;
    }

#pragma unroll
    for (int rg = 0; rg < 4; ++rg)
#pragma unroll
        for (int cg = 0; cg < 2; ++cg)
#pragma unroll
            for (int r = 0; r < 16; ++r) {
                const int row = brow + wr * 128 + rg * 32 + (r & 3) + 8 * (r >> 2) + 4 * hi5;
                const int col = bcol + wc * 64 + cg * 32 + l31;
                float v = acc[rg][cg][r];
                if (EPI == 0) {
                    v += aux[col];
                    v = fmaxf(v, 0.f);
                    u16 hi, lo; split2(v, hi, lo);
                    ((u16*)out0)[(size_t)row * N + col] = hi;
                    ((u16*)out1)[(size_t)row * N + col] = lo;
                } else if (EPI == 1) {
                    v += aux[col];
                    const int bb = row >> 9, cc = row & 511;
                    const size_t idx = ((size_t)bb * N + col) * 512 + cc;
                    u16 hi, lo; split2(v, hi, lo);
                    ((u16*)out0)[idx] = hi;
                    ((u16*)out1)[idx] = lo;
                } else if (EPI == 2) {
                    ((float*)out0)[(size_t)row * N + col] = v;
                } else {
                    ((float*)out0)[(size_t)z * strideO + (size_t)row * N + col] = v;
                }
            }
}

// ---------- elementwise split fp32 -> (hi,lo) bf16 ----------
__global__ void split_k(const float* __restrict__ in, u16* __restrict__ hi,
                        u16* __restrict__ lo, size_t n4)
{
    size_t i = blockIdx.x * (size_t)blockDim.x + threadIdx.x;
    const size_t stride = (size_t)gridDim.x * blockDim.x;
    for (; i < n4; i += stride) {
        const float4 v = ((const float4*)in)[i];
        ushort4 h, l;
        split2(v.x, h.x, l.x);
        split2(v.y, h.y, l.y);
        split2(v.z, h.z, l.z);
        split2(v.w, h.w, l.w);
        ((ushort4*)hi)[i] = h;
        ((ushort4*)lo)[i] = l;
    }
}

// ---------- plain fp32 -> bf16 convert ----------
__global__ void conv_bf16_k(const float* __restrict__ in, u16* __restrict__ out, size_t n4)
{
    size_t i = blockIdx.x * (size_t)blockDim.x + threadIdx.x;
    const size_t stride = (size_t)gridDim.x * blockDim.x;
    for (; i < n4; i += stride) {
        const float4 v = ((const float4*)in)[i];
        ushort4 o;
        o.x = f2bf_u(v.x); o.y = f2bf_u(v.y); o.z = f2bf_u(v.z); o.w = f2bf_u(v.w);
        ((ushort4*)out)[i] = o;
    }
}

// ---------- x (B,512,4096) -> xt (B,4096,512) with bf16 hi/lo split ----------
__global__ void transpose_split_x(const float* __restrict__ x,
                                  u16* __restrict__ xt_hi, u16* __restrict__ xt_lo)
{
    __shared__ float tile[32][33];
    const int b = blockIdx.z;
    const int n0 = blockIdx.x * 32;
    const int c0 = blockIdx.y * 32;
    const int tx = threadIdx.x, ty = threadIdx.y;   // block (32,8)
#pragma unroll
    for (int k = 0; k < 4; ++k)
        tile[ty + 8 * k][tx] = x[((size_t)b * 512 + c0 + ty + 8 * k) * 4096 + n0 + tx];
    __syncthreads();
#pragma unroll
    for (int k = 0; k < 4; ++k) {
        const float v = tile[tx][ty + 8 * k];       // [c_local][n_local]
        u16 hi, lo; split2(v, hi, lo);
        const size_t idx = ((size_t)b * 4096 + n0 + ty + 8 * k) * 512 + c0 + tx;
        xt_hi[idx] = hi;
        xt_lo[idx] = lo;
    }
}

// ---------- scale vector: s[n] = exp(min(ls[n], log(100))) ----------
__global__ void scale_prep(const float* __restrict__ ls, float* __restrict__ s)
{
    const int i = blockIdx.x * blockDim.x + threadIdx.x;
    if (i < 4096) s[i] = expf(fminf(ls[i], 4.605170185988092f));
}

// ---------- row softmax of tempT (4096 cols), row-scale s[m], write bf16 P ----------
__global__ __launch_bounds__(256)
void softmax_rows(const float* __restrict__ T, const float* __restrict__ s, u16* __restrict__ P)
{
    const int m = blockIdx.x;
    const int t = threadIdx.x;
    const float sc = s[m];
    const float* row = T + (size_t)m * 4096;
    float v[16];
    float mx = -3.402823e38f;
#pragma unroll
    for (int i = 0; i < 16; ++i) {
        v[i] = row[t + 256 * i] * sc;
        mx = fmaxf(mx, v[i]);
    }
#pragma unroll
    for (int o = 32; o; o >>= 1) mx = fmaxf(mx, __shfl_xor(mx, o, 64));
    __shared__ float sm[4], ss[4];
    if ((t & 63) == 0) sm[t >> 6] = mx;
    __syncthreads();
    mx = fmaxf(fmaxf(sm[0], sm[1]), fmaxf(sm[2], sm[3]));
    float sum = 0.f;
#pragma unroll
    for (int i = 0; i < 16; ++i) {
        v[i] = expf(v[i] - mx);
        sum += v[i];
    }
#pragma unroll
    for (int o = 32; o; o >>= 1) sum += __shfl_xor(sum, o, 64);
    if ((t & 63) == 0) ss[t >> 6] = sum;
    __syncthreads();
    sum = (ss[0] + ss[1]) + (ss[2] + ss[3]);
    const float inv = 1.f / sum;
#pragma unroll
    for (int i = 0; i < 16; ++i)
        P[(size_t)m * 4096 + t + 256 * i] = f2bf_u(v[i] * inv);
}

// ---------- LayerNorm rows of 4096 ----------
__global__ __launch_bounds__(256)
void ln_rows(const float* __restrict__ X, const float* __restrict__ gw,
             const float* __restrict__ gb, float* __restrict__ out)
{
    const int r = blockIdx.x;
    const int t = threadIdx.x;
    const float* row = X + (size_t)r * 4096;
    float v[16];
    float s1 = 0.f, s2 = 0.f;
#pragma unroll
    for (int i = 0; i < 16; ++i) {
        v[i] = row[t + 256 * i];
        s1 += v[i];
        s2 += v[i] * v[i];
    }
#pragma unroll
    for (int o = 32; o; o >>= 1) {
        s1 += __shfl_xor(s1, o, 64);
        s2 += __shfl_xor(s2, o, 64);
    }
    __shared__ float m1[4], m2[4];
    if ((t & 63) == 0) { m1[t >> 6] = s1; m2[t >> 6] = s2; }
    __syncthreads();
    s1 = (m1[0] + m1[1]) + (m1[2] + m1[3]);
    s2 = (m2[0] + m2[1]) + (m2[2] + m2[3]);
    const float mu = s1 * (1.f / 4096.f);
    const float var = s2 * (1.f / 4096.f) - mu * mu;
    const float rs = rsqrtf(var + 1e-5f);
#pragma unroll
    for (int i = 0; i < 16; ++i) {
        const int n = t + 256 * i;
        out[(size_t)r * 4096 + n] = (v[i] - mu) * rs * gw[n] + gb[n];
    }
}

extern "C" void kernel_launch(void* const* d_in, const int* in_sizes, int n_in,
                              void* d_out, int out_size, void* d_ws, size_t ws_size,
                              hipStream_t stream)
{
    const float* x  = (const float*)d_in[0];
    const float* fe = (const float*)d_in[1];
    const float* w1 = (const float*)d_in[2];
    const float* b1 = (const float*)d_in[3];
    const float* w2 = (const float*)d_in[4];
    const float* b2 = (const float*)d_in[5];
    const float* ls = (const float*)d_in[6];
    const float* nw = (const float*)d_in[7];
    const float* nb = (const float*)d_in[8];
    float* out = (float*)d_out;
    char* ws = (char*)d_ws;

    if (ws_size < 637550592ull) return;

    // Dynamic-LDS caps (host-side attribute, graph-capture safe).
    hipFuncSetAttribute((const void*)gemm256<0, true>,
                        hipFuncAttributeMaxDynamicSharedMemorySize, 147456);
    hipFuncSetAttribute((const void*)gemm256<1, true>,
                        hipFuncAttributeMaxDynamicSharedMemorySize, 147456);
    hipFuncSetAttribute((const void*)gemm256<2, true>,
                        hipFuncAttributeMaxDynamicSharedMemorySize, 147456);
    hipFuncSetAttribute((const void*)gemm256<3, false>,
                        hipFuncAttributeMaxDynamicSharedMemorySize, 98304);

    // Workspace plan (stream-order lifetime reuse):
    u16*  fhi  = (u16*) (ws + 0ull);
    u16*  flo  = (u16*) (ws + 134217728ull);
    u16*  w1hi = (u16*) (ws + 268435456ull);
    u16*  w1lo = (u16*) (ws + 402653184ull);
    u16*  hhi  = (u16*) (ws + 536870912ull);
    u16*  hlo  = (u16*) (ws + 570425344ull);
    u16*  w2hi = (u16*) (ws + 0ull);           // fe region dead after GEMM1
    u16*  w2lo = (u16*) (ws + 33554432ull);
    u16*  fthi = (u16*) (ws + 67108864ull);
    u16*  ftlo = (u16*) (ws + 100663296ull);
    u16*  xthi = (u16*) (ws + 134217728ull);
    u16*  xtlo = (u16*) (ws + 167772160ull);
    u16*  xbf  = (u16*) (ws + 201326592ull);
    float* tt  = (float*)(ws + 234881024ull);   // one-batch scores, fp32
    u16*  pall = (u16*) (ws + 301989888ull);    // P bf16, all batches
    float* pre = (float*)(ws + 570425344ull);   // pre-LN fp32 (h dead)
    float* sv  = (float*)(ws + 637534208ull);

    // 1. split feature and fc1_w
    split_k<<<2048, 256, 0, stream>>>(fe, fhi, flo, (size_t)16777216);
    split_k<<<2048, 256, 0, stream>>>(w1, w1hi, w1lo, (size_t)16777216);

    // 2. GEMM1: h = relu(feature @ fc1_w^T + b1), split-3, 32x32 MFMA
    gemm256<0, true><<<dim3(16, 16, 1), 512, 147456, stream>>>(
        fhi, flo, w1hi, w1lo, 16384, 16384, 4096, b1, hhi, hlo, 0, 0, 0);

    // 3. split fc2_w (fe region dead after GEMM1 in stream order)
    split_k<<<2048, 256, 0, stream>>>(w2, w2hi, w2lo, (size_t)4194304);

    // 4. GEMM2: feat = h @ fc2_w^T + b2, split scatter to ft[b][n][c]
    gemm256<1, true><<<dim3(16, 16, 1), 512, 147456, stream>>>(
        hhi, hlo, w2hi, w2lo, 4096, 4096, 4096, b2, fthi, ftlo, 0, 0, 0);

    // 5. x transforms + scale vector
    transpose_split_x<<<dim3(128, 16, 8), dim3(32, 8), 0, stream>>>(x, xthi, xtlo);
    conv_bf16_k<<<2048, 256, 0, stream>>>(x, xbf, (size_t)4194304);
    scale_prep<<<16, 256, 0, stream>>>(ls, sv);

    // 6. per batch: scores GEMM (split-3, K=512) + row softmax -> P
    for (int b = 0; b < 8; ++b) {
        const size_t o = (size_t)b * 4096 * 512;
        gemm256<2, true><<<dim3(16, 16, 1), 512, 147456, stream>>>(
            xthi + o, xtlo + o, fthi + o, ftlo + o, 512, 512, 4096,
            nullptr, tt, nullptr, 0, 0, 0);
        softmax_rows<<<4096, 256, 0, stream>>>(tt, sv, pall + (size_t)b * 16777216);
    }

    // 7. GEMM4: pre[b][c][m] = sum_n x[b][c][n] * P[b][m][n]   (plain bf16)
    gemm256<3, false><<<dim3(16, 2, 8), 512, 98304, stream>>>(
        xbf, nullptr, pall, nullptr, 4096, 4096, 4096, nullptr, pre, nullptr,
        (size_t)512 * 4096, (size_t)4096 * 4096, (size_t)512 * 4096);

    // 8. LayerNorm
    ln_rows<<<4096, 256, 0, stream>>>(pre, nw, nb, out);
}

// Round 10
// 2722.027 us; speedup vs baseline: 2.6149x; 1.0850x over previous
//
#include <hip/hip_runtime.h>
#include <stdint.h>

using u16 = unsigned short;
typedef unsigned int u32;
typedef __attribute__((ext_vector_type(4))) float f32x4;
typedef __attribute__((ext_vector_type(8))) short short8;

typedef const __attribute__((address_space(1))) u32* gas_ptr;
typedef __attribute__((address_space(3))) u32* las_ptr;

// ---------- bf16 helpers (bit-level, RNE) ----------
__device__ __forceinline__ u16 f2bf_u(float f) {
    u32 u = __builtin_bit_cast(u32, f);
    u32 r = 0x7fffu + ((u >> 16) & 1u);
    return (u16)((u + r) >> 16);
}
__device__ __forceinline__ float bfu2f(u16 h) {
    u32 u = ((u32)h) << 16;
    return __builtin_bit_cast(float, u);
}
__device__ __forceinline__ void split2(float v, u16& hi, u16& lo) {
    hi = f2bf_u(v);
    lo = f2bf_u(v - bfu2f(hi));   // exact residual, ~16 mantissa bits total
}

__device__ __forceinline__ void gload16(const void* g, void* l) {
    __builtin_amdgcn_global_load_lds((gas_ptr)g, (las_ptr)l, 16, 0, 0);
}

// ---------- GEMM-BT 256x256 tile, BK=32, 8 waves, mfma 16x16x32 ----------
// Round-6 proven pipeline (counted vmcnt, depth-2, 3 LDS buffers, 16x16 frag
// pattern = 0 bank conflicts) + intra-tile read/MFMA software pipelining:
// the 96 MFMA per wave-tile are split into 4 clusters of 24; cluster j's
// 4 ds_reads are issued during cluster j-1's MFMAs (one-cluster lookahead,
// static indices, ah_/al_ ping-pong), so the lgkm wait before each cluster
// is counted (lgkmcnt(4)), not a full drain. bh (4) + cluster0 (4) up front.
//   LDS: 3 bufs x {Ahi, Bhi, (Alo)}; Blo in per-wave register frags (BLOQ).
//   Per K-tile: s_waitcnt vmcnt(10|4) -> s_barrier -> STAGE(kt+2) -> reads
//   + clustered MFMA -> BLOQ(kt+2). vmcnt never drains to 0 mid-loop.
// Ledger (SPLIT): groups per tile = [S:6 gload_lds][Q:4 reg loads]; at tile t
// top, outstanding = S(t),Q(t),S(t+1),Q(t+1)=20 -> wait 10 leaves S/Q(t+1).
// Tail t=NT-1 -> vmcnt(0). Non-split: S=4 -> wait 4 / 0.
// LDS chunk swizzle (verified 0 conflicts): slot (row,c) holds global chunk
// c ^ ((row>>1)&3); staged via pre-swizzled GLOBAL source (LDS dest linear,
// global_load_lds rule), read with matching XOR.
// EPI 0: v=acc+aux[col]; relu; bf16 split write (out0=hi,out1=lo), [M][N]
// EPI 1: v=acc+aux[col]; bf16 split scatter to [b][col][c] (b=row>>9,c=row&511)
// EPI 2: fp32 row-major write (scores; per-row scale applied in softmax)
// EPI 3: fp32 write with batch stride (preLN)

#define STAGE(CBUF, KT)                                                      \
  {                                                                          \
    const int kk_ = (KT) << 5;                                               \
    _Pragma("unroll")                                                        \
    for (int it_ = 0; it_ < 2; ++it_) {                                      \
      const int rb_ = it_ * 128 + w * 16;                                    \
      const int lo_ = (CBUF) * 8192 + rb_ * 32;                              \
      const size_t ga_ = (size_t)(brow + rb_ + srow) * lda + (kk_ + sca);    \
      const size_t gb_ = (size_t)(bcol + rb_ + srow) * lda + (kk_ + sca);    \
      gload16(A0 + ga_, &As0[lo_]);                                          \
      gload16(B0 + gb_, &Bs0[lo_]);                                          \
      if constexpr (SPLIT) gload16(A1 + ga_, &As1[lo_]);                     \
    }                                                                        \
  }

#define BLOQ(Q, KT)                                                          \
  {                                                                          \
    const u16* bb_ = B1 + (size_t)(bcol + wc * 64 + lr) * lda                \
                     + (((KT) << 5) + ((l >> 4) * 8));                       \
    _Pragma("unroll")                                                        \
    for (int n_ = 0; n_ < 4; ++n_)                                           \
      Q[n_] = *(const short8*)(bb_ + (size_t)(n_ * 16) * lda);               \
  }

// a-frag I (0..7): LDS row = wave_row_base + (I>>2)*64 + (I&3)*16 + lr
// (lrw = wr*128 + lr precomputed). cbv_ is PHASE's local buffer index.
#define AREAD(DSTH, DSTL, I)                                                 \
  {                                                                          \
    const int ro_ = cbv_ * 8192 +                                            \
        (lrw + (((I) >> 2) * 64 + ((I) & 3) * 16)) * 32 + cr;                \
    DSTH = *(const short8*)&As0[ro_];                                        \
    if constexpr (SPLIT) DSTL = *(const short8*)&As1[ro_];                   \
  }

#define PHASE(KT, CB, Q)                                                     \
  {                                                                          \
    const int cbv_ = (CB);                                                   \
    if ((KT) == NT - 1) {                                                    \
      asm volatile("s_waitcnt vmcnt(0)" ::: "memory");                       \
    } else {                                                                 \
      if constexpr (SPLIT) asm volatile("s_waitcnt vmcnt(10)" ::: "memory"); \
      else asm volatile("s_waitcnt vmcnt(4)" ::: "memory");                  \
    }                                                                        \
    __builtin_amdgcn_s_barrier();                                            \
    __builtin_amdgcn_sched_barrier(0);                                       \
    {                                                                        \
      int cs_ = cbv_ + 2; if (cs_ >= 3) cs_ -= 3;                            \
      if ((KT) + 2 < NT) STAGE(cs_, (KT) + 2);                               \
    }                                                                        \
    short8 bh_[4];                                                           \
    _Pragma("unroll")                                                        \
    for (int n_ = 0; n_ < 4; ++n_)                                           \
      bh_[n_] = *(const short8*)&Bs0[cbv_ * 8192 +                           \
                                     (wc * 64 + n_ * 16 + lr) * 32 + cr];    \
    short8 ah_[2][2], al_[2][2];                                             \
    AREAD(ah_[0][0], al_[0][0], 0);                                          \
    AREAD(ah_[0][1], al_[0][1], 1);                                          \
    __builtin_amdgcn_sched_barrier(0);                                       \
    _Pragma("unroll")                                                        \
    for (int j_ = 0; j_ < 4; ++j_) {                                         \
      const int p_ = j_ & 1;                                                 \
      if (j_ < 3) {                                                          \
        AREAD(ah_[p_ ^ 1][0], al_[p_ ^ 1][0], 2 * j_ + 2);                   \
        AREAD(ah_[p_ ^ 1][1], al_[p_ ^ 1][1], 2 * j_ + 3);                   \
      }                                                                      \
      __builtin_amdgcn_sched_barrier(0);                                     \
      __builtin_amdgcn_s_setprio(1);                                         \
      _Pragma("unroll")                                                      \
      for (int ii_ = 0; ii_ < 2; ++ii_) {                                    \
        const int i_ = 2 * j_ + ii_;                                         \
        _Pragma("unroll")                                                    \
        for (int n_ = 0; n_ < 4; ++n_)                                       \
          acc[i_][n_] = __builtin_amdgcn_mfma_f32_16x16x32_bf16(             \
              ah_[p_][ii_], bh_[n_], acc[i_][n_], 0, 0, 0);                  \
        if constexpr (SPLIT) {                                               \
          _Pragma("unroll")                                                  \
          for (int n_ = 0; n_ < 4; ++n_)                                     \
            acc[i_][n_] = __builtin_amdgcn_mfma_f32_16x16x32_bf16(           \
                al_[p_][ii_], bh_[n_], acc[i_][n_], 0, 0, 0);                \
          _Pragma("unroll")                                                  \
          for (int n_ = 0; n_ < 4; ++n_)                                     \
            acc[i_][n_] = __builtin_amdgcn_mfma_f32_16x16x32_bf16(           \
                ah_[p_][ii_], Q[n_], acc[i_][n_], 0, 0, 0);                  \
        }                                                                    \
      }                                                                      \
      __builtin_amdgcn_s_setprio(0);                                         \
    }                                                                        \
    __builtin_amdgcn_sched_barrier(0);                                       \
    if ((KT) + 2 < NT) { if constexpr (SPLIT) BLOQ(Q, (KT) + 2); }           \
    __builtin_amdgcn_sched_barrier(0);                                       \
  }

template<int EPI, bool SPLIT>
__global__ __launch_bounds__(512, 2)
void gemm256(const u16* __restrict__ Ah, const u16* __restrict__ Al,
             const u16* __restrict__ Bh, const u16* __restrict__ Bl,
             int K, int lda, int N,
             const float* __restrict__ aux,
             void* __restrict__ out0, void* __restrict__ out1,
             size_t strideA, size_t strideB, size_t strideO)
{
    extern __shared__ __align__(16) u16 lds[];
    u16* const As0 = lds;                                   // [3][8192]
    u16* const Bs0 = lds + 3 * 8192;                        // [3][8192]
    u16* const As1 = SPLIT ? (lds + 6 * 8192) : lds;        // [3][8192]

    const int t = threadIdx.x;
    const int w = t >> 6;
    const int l = t & 63;

    // Block swizzle. 16x16 grids: 4x8 region per XCD; other grids: generic
    // XCD-chunked bijective swizzle (nwg % 8 == 0).
    int brow, bcol;
    const int gx = gridDim.x, gy = gridDim.y;
    const int orig = blockIdx.y * gx + blockIdx.x;
    if (gx == 16 && gy == 16) {
        const int x = orig & 7, j = orig >> 3;
        brow = ((x & 3) * 4 + (j & 3)) * 256;
        bcol = ((x >> 2) * 8 + (j >> 2)) * 256;
    } else {
        const int nwg = gx * gy;
        const int swz = (orig & 7) * (nwg >> 3) + (orig >> 3);
        brow = (swz / gx) * 256;
        bcol = (swz % gx) * 256;
    }
    const int z = blockIdx.z;

    const u16* A0 = Ah + (size_t)z * strideA;
    const u16* A1 = SPLIT ? (Al + (size_t)z * strideA) : nullptr;
    const u16* B0 = Bh + (size_t)z * strideB;
    const u16* B1 = SPLIT ? (Bl + (size_t)z * strideB) : nullptr;

    // staging: lane l covers row l>>2 (of 16), LDS chunk l&3;
    // global chunk = (l&3) ^ ((row>>1)&3) = (l&3) ^ ((l>>3)&3)
    const int srow = l >> 2;
    const int sca = ((l & 3) ^ ((l >> 3) & 3)) * 8;

    // wave grid 2(M) x 4(N)
    const int wr = w >> 2;
    const int wc = w & 3;
    const int lr = l & 15;
    // frag read swizzle: slot chunk = (l>>4) ^ ((row>>1)&3), row%16 = lr
    const int cr = ((l >> 4) ^ ((l >> 1) & 3)) * 8;
    const int lrw = wr * 128 + lr;   // wave A-row base + lane row

    f32x4 acc[8][4];
    const f32x4 zero = {0.f, 0.f, 0.f, 0.f};
#pragma unroll
    for (int i = 0; i < 8; ++i)
#pragma unroll
        for (int j = 0; j < 4; ++j) acc[i][j] = zero;

    const int NT = K >> 5;
    short8 qA[4], qB[4];

    // prologue: S(0), Q(0), S(1), Q(1); wait S(0); barrier
    STAGE(0, 0);
    if constexpr (SPLIT) BLOQ(qA, 0);
    STAGE(1, 1);
    if constexpr (SPLIT) BLOQ(qB, 1);
    if constexpr (SPLIT)
        asm volatile("s_waitcnt vmcnt(10)" ::: "memory");
    else
        asm volatile("s_waitcnt vmcnt(4)" ::: "memory");
    __builtin_amdgcn_s_barrier();
    __builtin_amdgcn_sched_barrier(0);

    int cb = 0;
    for (int kt = 0; kt < NT; kt += 2) {
        PHASE(kt, cb, qA);
        cb = (cb == 2) ? 0 : cb + 1;
        PHASE(kt + 1, cb, qB);
        cb = (cb == 2) ? 0 : cb + 1;
    }

#pragma unroll
    for (int mh = 0; mh < 2; ++mh)
#pragma unroll
        for (int m = 0; m < 4; ++m)
#pragma unroll
            for (int n = 0; n < 4; ++n)
#pragma unroll
                for (int j = 0; j < 4; ++j) {
                    const int row = brow + wr * 128 + mh * 64 + m * 16 + (l >> 4) * 4 + j;
                    const int col = bcol + wc * 64 + n * 16 + (l & 15);
                    float v = acc[mh * 4 + m][n][j];
                    if (EPI == 0) {
                        v += aux[col];
                        v = fmaxf(v, 0.f);
                        u16 hi, lo; split2(v, hi, lo);
                        ((u16*)out0)[(size_t)row * N + col] = hi;
                        ((u16*)out1)[(size_t)row * N + col] = lo;
                    } else if (EPI == 1) {
                        v += aux[col];
                        const int bb = row >> 9, cc = row & 511;
                        const size_t idx = ((size_t)bb * N + col) * 512 + cc;
                        u16 hi, lo; split2(v, hi, lo);
                        ((u16*)out0)[idx] = hi;
                        ((u16*)out1)[idx] = lo;
                    } else if (EPI == 2) {
                        ((float*)out0)[(size_t)row * N + col] = v;
                    } else {
                        ((float*)out0)[(size_t)z * strideO + (size_t)row * N + col] = v;
                    }
                }
}

// ---------- elementwise split fp32 -> (hi,lo) bf16 ----------
__global__ void split_k(const float* __restrict__ in, u16* __restrict__ hi,
                        u16* __restrict__ lo, size_t n4)
{
    size_t i = blockIdx.x * (size_t)blockDim.x + threadIdx.x;
    const size_t stride = (size_t)gridDim.x * blockDim.x;
    for (; i < n4; i += stride) {
        const float4 v = ((const float4*)in)[i];
        ushort4 h, l;
        split2(v.x, h.x, l.x);
        split2(v.y, h.y, l.y);
        split2(v.z, h.z, l.z);
        split2(v.w, h.w, l.w);
        ((ushort4*)hi)[i] = h;
        ((ushort4*)lo)[i] = l;
    }
}

// ---------- plain fp32 -> bf16 convert ----------
__global__ void conv_bf16_k(const float* __restrict__ in, u16* __restrict__ out, size_t n4)
{
    size_t i = blockIdx.x * (size_t)blockDim.x + threadIdx.x;
    const size_t stride = (size_t)gridDim.x * blockDim.x;
    for (; i < n4; i += stride) {
        const float4 v = ((const float4*)in)[i];
        ushort4 o;
        o.x = f2bf_u(v.x); o.y = f2bf_u(v.y); o.z = f2bf_u(v.z); o.w = f2bf_u(v.w);
        ((ushort4*)out)[i] = o;
    }
}

// ---------- x (B,512,4096) -> xt (B,4096,512) with bf16 hi/lo split ----------
__global__ void transpose_split_x(const float* __restrict__ x,
                                  u16* __restrict__ xt_hi, u16* __restrict__ xt_lo)
{
    __shared__ float tile[32][33];
    const int b = blockIdx.z;
    const int n0 = blockIdx.x * 32;
    const int c0 = blockIdx.y * 32;
    const int tx = threadIdx.x, ty = threadIdx.y;   // block (32,8)
#pragma unroll
    for (int k = 0; k < 4; ++k)
        tile[ty + 8 * k][tx] = x[((size_t)b * 512 + c0 + ty + 8 * k) * 4096 + n0 + tx];
    __syncthreads();
#pragma unroll
    for (int k = 0; k < 4; ++k) {
        const float v = tile[tx][ty + 8 * k];       // [c_local][n_local]
        u16 hi, lo; split2(v, hi, lo);
        const size_t idx = ((size_t)b * 4096 + n0 + ty + 8 * k) * 512 + c0 + tx;
        xt_hi[idx] = hi;
        xt_lo[idx] = lo;
    }
}

// ---------- scale vector: s[n] = exp(min(ls[n], log(100))) ----------
__global__ void scale_prep(const float* __restrict__ ls, float* __restrict__ s)
{
    const int i = blockIdx.x * blockDim.x + threadIdx.x;
    if (i < 4096) s[i] = expf(fminf(ls[i], 4.605170185988092f));
}

// ---------- row softmax of tempT (4096 cols), row-scale s[m], write bf16 P ----------
__global__ __launch_bounds__(256)
void softmax_rows(const float* __restrict__ T, const float* __restrict__ s, u16* __restrict__ P)
{
    const int m = blockIdx.x;
    const int t = threadIdx.x;
    const float sc = s[m];
    const float* row = T + (size_t)m * 4096;
    float v[16];
    float mx = -3.402823e38f;
#pragma unroll
    for (int i = 0; i < 16; ++i) {
        v[i] = row[t + 256 * i] * sc;
        mx = fmaxf(mx, v[i]);
    }
#pragma unroll
    for (int o = 32; o; o >>= 1) mx = fmaxf(mx, __shfl_xor(mx, o, 64));
    __shared__ float sm[4], ss[4];
    if ((t & 63) == 0) sm[t >> 6] = mx;
    __syncthreads();
    mx = fmaxf(fmaxf(sm[0], sm[1]), fmaxf(sm[2], sm[3]));
    float sum = 0.f;
#pragma unroll
    for (int i = 0; i < 16; ++i) {
        v[i] = expf(v[i] - mx);
        sum += v[i];
    }
#pragma unroll
    for (int o = 32; o; o >>= 1) sum += __shfl_xor(sum, o, 64);
    if ((t & 63) == 0) ss[t >> 6] = sum;
    __syncthreads();
    sum = (ss[0] + ss[1]) + (ss[2] + ss[3]);
    const float inv = 1.f / sum;
#pragma unroll
    for (int i = 0; i < 16; ++i)
        P[(size_t)m * 4096 + t + 256 * i] = f2bf_u(v[i] * inv);
}

// ---------- LayerNorm rows of 4096 ----------
__global__ __launch_bounds__(256)
void ln_rows(const float* __restrict__ X, const float* __restrict__ gw,
             const float* __restrict__ gb, float* __restrict__ out)
{
    const int r = blockIdx.x;
    const int t = threadIdx.x;
    const float* row = X + (size_t)r * 4096;
    float v[16];
    float s1 = 0.f, s2 = 0.f;
#pragma unroll
    for (int i = 0; i < 16; ++i) {
        v[i] = row[t + 256 * i];
        s1 += v[i];
        s2 += v[i] * v[i];
    }
#pragma unroll
    for (int o = 32; o; o >>= 1) {
        s1 += __shfl_xor(s1, o, 64);
        s2 += __shfl_xor(s2, o, 64);
    }
    __shared__ float m1[4], m2[4];
    if ((t & 63) == 0) { m1[t >> 6] = s1; m2[t >> 6] = s2; }
    __syncthreads();
    s1 = (m1[0] + m1[1]) + (m1[2] + m1[3]);
    s2 = (m2[0] + m2[1]) + (m2[2] + m2[3]);
    const float mu = s1 * (1.f / 4096.f);
    const float var = s2 * (1.f / 4096.f) - mu * mu;
    const float rs = rsqrtf(var + 1e-5f);
#pragma unroll
    for (int i = 0; i < 16; ++i) {
        const int n = t + 256 * i;
        out[(size_t)r * 4096 + n] = (v[i] - mu) * rs * gw[n] + gb[n];
    }
}

extern "C" void kernel_launch(void* const* d_in, const int* in_sizes, int n_in,
                              void* d_out, int out_size, void* d_ws, size_t ws_size,
                              hipStream_t stream)
{
    const float* x  = (const float*)d_in[0];
    const float* fe = (const float*)d_in[1];
    const float* w1 = (const float*)d_in[2];
    const float* b1 = (const float*)d_in[3];
    const float* w2 = (const float*)d_in[4];
    const float* b2 = (const float*)d_in[5];
    const float* ls = (const float*)d_in[6];
    const float* nw = (const float*)d_in[7];
    const float* nb = (const float*)d_in[8];
    float* out = (float*)d_out;
    char* ws = (char*)d_ws;

    if (ws_size < 637550592ull) return;

    // Dynamic-LDS caps (host-side attribute, graph-capture safe).
    hipFuncSetAttribute((const void*)gemm256<0, true>,
                        hipFuncAttributeMaxDynamicSharedMemorySize, 147456);
    hipFuncSetAttribute((const void*)gemm256<1, true>,
                        hipFuncAttributeMaxDynamicSharedMemorySize, 147456);
    hipFuncSetAttribute((const void*)gemm256<2, true>,
                        hipFuncAttributeMaxDynamicSharedMemorySize, 147456);
    hipFuncSetAttribute((const void*)gemm256<3, false>,
                        hipFuncAttributeMaxDynamicSharedMemorySize, 98304);

    // Workspace plan (stream-order lifetime reuse):
    u16*  fhi  = (u16*) (ws + 0ull);
    u16*  flo  = (u16*) (ws + 134217728ull);
    u16*  w1hi = (u16*) (ws + 268435456ull);
    u16*  w1lo = (u16*) (ws + 402653184ull);
    u16*  hhi  = (u16*) (ws + 536870912ull);
    u16*  hlo  = (u16*) (ws + 570425344ull);
    u16*  w2hi = (u16*) (ws + 0ull);           // fe region dead after GEMM1
    u16*  w2lo = (u16*) (ws + 33554432ull);
    u16*  fthi = (u16*) (ws + 67108864ull);
    u16*  ftlo = (u16*) (ws + 100663296ull);
    u16*  xthi = (u16*) (ws + 134217728ull);
    u16*  xtlo = (u16*) (ws + 167772160ull);
    u16*  xbf  = (u16*) (ws + 201326592ull);
    float* tt  = (float*)(ws + 234881024ull);   // one-batch scores, fp32
    u16*  pall = (u16*) (ws + 301989888ull);    // P bf16, all batches
    float* pre = (float*)(ws + 570425344ull);   // pre-LN fp32 (h dead)
    float* sv  = (float*)(ws + 637534208ull);

    // 1. split feature and fc1_w
    split_k<<<2048, 256, 0, stream>>>(fe, fhi, flo, (size_t)16777216);
    split_k<<<2048, 256, 0, stream>>>(w1, w1hi, w1lo, (size_t)16777216);

    // 2. GEMM1: h = relu(feature @ fc1_w^T + b1), split-3, clustered pipeline
    gemm256<0, true><<<dim3(16, 16, 1), 512, 147456, stream>>>(
        fhi, flo, w1hi, w1lo, 16384, 16384, 4096, b1, hhi, hlo, 0, 0, 0);

    // 3. split fc2_w (fe region dead after GEMM1 in stream order)
    split_k<<<2048, 256, 0, stream>>>(w2, w2hi, w2lo, (size_t)4194304);

    // 4. GEMM2: feat = h @ fc2_w^T + b2, split scatter to ft[b][n][c]
    gemm256<1, true><<<dim3(16, 16, 1), 512, 147456, stream>>>(
        hhi, hlo, w2hi, w2lo, 4096, 4096, 4096, b2, fthi, ftlo, 0, 0, 0);

    // 5. x transforms + scale vector
    transpose_split_x<<<dim3(128, 16, 8), dim3(32, 8), 0, stream>>>(x, xthi, xtlo);
    conv_bf16_k<<<2048, 256, 0, stream>>>(x, xbf, (size_t)4194304);
    scale_prep<<<16, 256, 0, stream>>>(ls, sv);

    // 6. per batch: scores GEMM (split-3, K=512) + row softmax -> P
    for (int b = 0; b < 8; ++b) {
        const size_t o = (size_t)b * 4096 * 512;
        gemm256<2, true><<<dim3(16, 16, 1), 512, 147456, stream>>>(
            xthi + o, xtlo + o, fthi + o, ftlo + o, 512, 512, 4096,
            nullptr, tt, nullptr, 0, 0, 0);
        softmax_rows<<<4096, 256, 0, stream>>>(tt, sv, pall + (size_t)b * 16777216);
    }

    // 7. GEMM4: pre[b][c][m] = sum_n x[b][c][n] * P[b][m][n]   (plain bf16)
    gemm256<3, false><<<dim3(16, 2, 8), 512, 98304, stream>>>(
        xbf, nullptr, pall, nullptr, 4096, 4096, 4096, nullptr, pre, nullptr,
        (size_t)512 * 4096, (size_t)4096 * 4096, (size_t)512 * 4096);

    // 8. LayerNorm
    ln_rows<<<4096, 256, 0, stream>>>(pre, nw, nb, out);
}